// Round 9
// baseline (339.082 us; speedup 1.0000x reference)
//
#include <hip/hip_runtime.h>

typedef short bf16x8 __attribute__((ext_vector_type(8)));
typedef float f32x4 __attribute__((ext_vector_type(4)));
typedef unsigned short u16;

__device__ __forceinline__ u16 f2bf(float f) {
    unsigned u = __builtin_bit_cast(unsigned, f);
    return (u16)((u + 0x7fffu + ((u >> 16) & 1u)) >> 16);   // RNE
}

// ---------------- kernel 1 (fused prep + W build) ----------------------------
// blocks [0,1024):     xpad[b][r][d] bf16 (r<4096 zeros, 4096+t = x[b,t,:])
// blocks [1024,1152):  zero d_out (2 MiB); block 1024 also zeros the counter
// blocks [1152,3200):  build Wtot[s][o][d] bf16, 32 s x 256 q per block:
//   W[s][o][d] = sum_k phi[s,k]*(Mp + sgn(s)*Mm)[k,d,o]  (+ M[o,d,s] for s<3)
//   phi staged in LDS (broadcast f32x4 reads); Ap/Am from L2-resident Mp/Mm.
__global__ __launch_bounds__(256)
void k_prepbuild(const float* __restrict__ x, u16* __restrict__ xpad,
                 const float* __restrict__ phi,
                 const float* __restrict__ Mp, const float* __restrict__ Mm,
                 const float* __restrict__ Mar, u16* __restrict__ wg,
                 float* __restrict__ out, int* __restrict__ counter) {
    __shared__ __align__(16) float phis[32 * 40];        // 5 KB
    if (blockIdx.x < 1024) {
        int gid = blockIdx.x * 256 + threadIdx.x;
        int b   = gid >> 17;
        int rem = gid & 131071;
        int r   = rem >> 4;
        int c4  = rem & 15;
        u16 o0 = 0, o1 = 0, o2 = 0, o3 = 0;
        if (r >= 4096) {
            const f32x4 v = *(const f32x4*)(x + ((b << 12) + (r - 4096)) * 64 + c4 * 4);
            o0 = f2bf(v.x); o1 = f2bf(v.y); o2 = f2bf(v.z); o3 = f2bf(v.w);
        }
        u16* p = xpad + ((b << 13) + r) * 64 + c4 * 4;
        p[0] = o0; p[1] = o1; p[2] = o2; p[3] = o3;
    } else if (blockIdx.x < 1152) {
        const int bz = blockIdx.x - 1024;                // 128 blocks x 4096 floats
        if (bz == 0 && threadIdx.x == 0) *counter = 0;
        float* po = out + bz * 4096;
        #pragma unroll
        for (int i = 0; i < 4; ++i)
            *(f32x4*)(po + (threadIdx.x + i * 256) * 4) = (f32x4){0.f, 0.f, 0.f, 0.f};
    } else {
        const int bi = blockIdx.x - 1152;
        const int sb = bi >> 4, qb = bi & 15;
        const int s0 = sb * 32;
        const int q  = qb * 256 + threadIdx.x;
        const int o  = q >> 6, d = q & 63;

        for (int f = threadIdx.x; f < 1280; f += 256) phis[f] = phi[s0 * 40 + f];

        float ap[40], am[40];
        #pragma unroll
        for (int k = 0; k < 40; ++k) {
            float p = Mp[k * 4096 + d * 64 + o];         // L2-resident (1.3 MB)
            float m = Mm[k * 4096 + d * 64 + o];
            ap[k] = p + m; am[k] = p - m;
        }
        __syncthreads();

        for (int j = 0; j < 32; j += 2) {
            const float* ph = phis + j * 40;             // wave-uniform broadcast
            float ev = 0.f, ov = 0.f;
            #pragma unroll
            for (int k = 0; k < 40; k += 4) {
                f32x4 p0 = *(const f32x4*)(ph + k);
                f32x4 p1 = *(const f32x4*)(ph + 40 + k);
                ev += p0.x * ap[k] + p0.y * ap[k + 1] + p0.z * ap[k + 2] + p0.w * ap[k + 3];
                ov += p1.x * am[k] + p1.y * am[k + 1] + p1.z * am[k + 2] + p1.w * am[k + 3];
            }
            int s = s0 + j;
            if (s < 3)     ev += Mar[o * 192 + d * 3 + s];
            if (s + 1 < 3) ov += Mar[o * 192 + d * 3 + s + 1];
            wg[(size_t)s * 4096 + q]       = f2bf(ev);
            wg[(size_t)(s + 1) * 4096 + q] = f2bf(ov);
        }
    }
}

// ---------------- kernel 2: triangular conv-GEMM, s-parity waves -------------
// R7 inner geometry (best measured, 0 conflicts): wave=(s-parity,batch),
// mt=8 x nt=4, 64-s tiles, J-major dynamic order + 32-s tail taper.
// R9: W s-pair DOUBLE-buffered (2 pairs, 32 KB) -> 1 barrier per j (was 2).
__global__ __launch_bounds__(256, 2)
void k_spectral(const u16* __restrict__ xpad, const u16* __restrict__ wg,
                float* __restrict__ out, int* __restrict__ counter) {
    __shared__ __align__(16) u16 xs[2 * 191 * 64];       // 47.75 KB x window
    __shared__ __align__(16) u16 wsm[4 * 64 * 64];       // 32 KB: 2 pairs of W tiles
    __shared__ int sh;

    const int tid  = threadIdx.x;
    const int lane = tid & 63, w = tid >> 6;
    const int m15  = lane & 15, q4 = lane >> 4;
    const int par  = w >> 1, batch = w & 1;              // wave = (parity, batch)
    const int f0 = tid * 2, f1 = tid * 2 + 1;            // W staging granules
    const int l0 = (((f0 >> 3) * 8) + ((f0 & 7) ^ ((f0 >> 3) & 7))) * 8;
    const int l1 = (((f1 >> 3) * 8) + ((f1 & 7) ^ ((f1 >> 3) & 7))) * 8;

    for (;;) {
        __syncthreads();                                 // xs/wsm/sh reuse guard
        if (tid == 0) sh = atomicAdd(counter, 1);
        __syncthreads();
        const int U = sh;
        if (U >= 1120) break;

        // taper: U<992 -> full unit; else half task (32-s) of unit 992+(U-992)/2
        int mu = U, shalf = 0, slen = 64;
        if (U >= 992) { mu = 992 + ((U - 992) >> 1); shalf = (U - 992) & 1; slen = 32; }
        // J-major unit decode: group g=J>>1, G(g)=g(65-g), column cnt=32-g
        int g = 0;
        #pragma unroll 1
        while (g < 31 && (g + 1) * (64 - g) <= mu) ++g;
        const int rem = mu - g * (65 - g);
        const int cnt = 32 - g;
        const int col = (rem >= cnt) ? 1 : 0;
        const int J = 2 * g + col;
        const int I = g + (col ? rem - cnt : rem);
        const int t0 = I << 7, s0 = (J << 6) + (shalf << 5);
        const int nrows = 127 + slen;
        const int jmax = slen >> 1;
        const int base = 4096 + t0 - s0 - (slen - 1);    // window start row in xpad

        // prefetch W pair (s0, s0+1)
        const u16* wbase = wg + (size_t)s0 * 4096;
        bf16x8 pre[4];
        pre[0] = *(const bf16x8*)(wbase + f0 * 8);
        pre[1] = *(const bf16x8*)(wbase + f1 * 8);
        pre[2] = *(const bf16x8*)(wbase + 4096 + f0 * 8);
        pre[3] = *(const bf16x8*)(wbase + 4096 + f1 * 8);

        // ---- stage x window: nrows rows/batch ----
        #pragma unroll
        for (int b = 0; b < 2; ++b) {
            #pragma unroll 1
            for (int f = tid; f < nrows * 8; f += 256) {
                int r = f >> 3, c = f & 7;
                bf16x8 v = *(const bf16x8*)(xpad + (size_t)((b << 13) + base + r) * 64 + c * 8);
                *(bf16x8*)(xs + ((b * 191 + r) * 8 + (c ^ (r & 7))) * 8) = v;
            }
        }

        f32x4 acc[8][4];
        #pragma unroll
        for (int mt = 0; mt < 8; ++mt)
            #pragma unroll
            for (int nt = 0; nt < 4; ++nt)
                acc[mt][nt] = (f32x4){0.f, 0.f, 0.f, 0.f};

        const u16* xb = xs + batch * (191 * 64);

        #pragma unroll 1
        for (int j = 0; j < jmax; ++j) {
            u16* wdst = wsm + (j & 1) * 8192;            // idle pair -> no pre-barrier
            *(bf16x8*)(wdst + l0)        = pre[0];
            *(bf16x8*)(wdst + l1)        = pre[1];
            *(bf16x8*)(wdst + 4096 + l0) = pre[2];
            *(bf16x8*)(wdst + 4096 + l1) = pre[3];
            __syncthreads();                             // pair visible; old reads retired
            if (j < jmax - 1) {                          // prefetch next pair
                const u16* wp = wbase + (size_t)(2 * j + 2) * 4096;
                pre[0] = *(const bf16x8*)(wp + f0 * 8);
                pre[1] = *(const bf16x8*)(wp + f1 * 8);
                pre[2] = *(const bf16x8*)(wp + 4096 + f0 * 8);
                pre[3] = *(const bf16x8*)(wp + 4096 + f1 * 8);
            }
            const u16* wpar = wsm + (j & 1) * 8192 + par * 4096;
            const int ds = 2 * j + par;                  // this wave's s offset
            #pragma unroll
            for (int ks = 0; ks < 2; ++ks) {
                const int kq = ks * 4 + q4;
                bf16x8 bf[4];
                #pragma unroll
                for (int nt = 0; nt < 4; ++nt) {
                    int o = nt * 16 + m15;
                    bf[nt] = *(const bf16x8*)(wpar + (o * 8 + (kq ^ (o & 7))) * 8);
                }
                #pragma unroll
                for (int mt = 0; mt < 8; ++mt) {
                    int r = mt * 16 + m15 + (slen - 1) - ds;   // in [0, nrows-1]
                    bf16x8 av = *(const bf16x8*)(xb + (r * 8 + (kq ^ (r & 7))) * 8);
                    #pragma unroll
                    for (int nt = 0; nt < 4; ++nt)
                        acc[mt][nt] = __builtin_amdgcn_mfma_f32_16x16x32_bf16(
                            av, bf[nt], acc[mt][nt], 0, 0, 0);
                }
            }
        }

        // ---- merge parity-1 partials into parity-0 accs via LDS (wsm dead) ----
        float* fs = (float*)wsm;                         // 4096 floats (16 KB)
        #pragma unroll
        for (int rd = 0; rd < 4; ++rd) {
            __syncthreads();
            if (par == 1) {
                #pragma unroll
                for (int i = 0; i < 8; ++i) {
                    int ti = rd * 8 + i;
                    *(f32x4*)(fs + (batch * 8 + i) * 256 + lane * 4) = acc[ti >> 2][ti & 3];
                }
            }
            __syncthreads();
            if (par == 0) {
                #pragma unroll
                for (int i = 0; i < 8; ++i) {
                    int ti = rd * 8 + i;
                    f32x4 v = *(const f32x4*)(fs + (batch * 8 + i) * 256 + lane * 4);
                    acc[ti >> 2][ti & 3] += v;
                }
            }
        }

        // ---- epilogue (parity-0 waves only): coalesced fp32 atomics ----
        if (par == 0) {
            #pragma unroll
            for (int mt = 0; mt < 8; ++mt) {
                int t = t0 + mt * 16 + q4 * 4;
                #pragma unroll
                for (int nt = 0; nt < 4; ++nt) {
                    int o = nt * 16 + m15;
                    float* op = out + (size_t)((batch << 12) + t) * 64 + o;
                    #pragma unroll
                    for (int r = 0; r < 4; ++r)
                        atomicAdd(op + r * 64, acc[mt][nt][r]);
                }
            }
        }
    }
}

// ---------------------------------------------------------------------------
extern "C" void kernel_launch(void* const* d_in, const int* in_sizes, int n_in,
                              void* d_out, int out_size, void* d_ws, size_t ws_size,
                              hipStream_t stream) {
    const float* x   = (const float*)d_in[0];   // (2, 4096, 64)
    const float* phi = (const float*)d_in[1];   // (4096, 40)
    const float* M   = (const float*)d_in[2];   // (64, 64, 3)
    const float* Mp  = (const float*)d_in[3];   // (40, 64, 64)
    const float* Mm  = (const float*)d_in[4];   // (40, 64, 64)
    float* out = (float*)d_out;                 // (2, 4096, 64)

    // ws: [0,4) counter | 4096: xpad 2 MiB | wg 32 MiB
    int* counter = (int*)d_ws;
    u16* xpad = (u16*)((char*)d_ws + 4096);
    u16* wg   = (u16*)((char*)d_ws + 4096 + 2097152);

    k_prepbuild<<<3200, 256, 0, stream>>>(x, xpad, phi, Mp, Mm, M, wg, out, counter);
    k_spectral<<<512, 256, 0, stream>>>(xpad, wg, out, counter);
}